// Round 7
// baseline (797.911 us; speedup 1.0000x reference)
//
#include <hip/hip_runtime.h>
#include <math.h>

#define N_PTS 32768
#define DIM   512
#define K_CL  64
#define ITERS 10
#define EPS_F 1e-8f

typedef __attribute__((ext_vector_type(8))) short          short8v;
typedef __attribute__((ext_vector_type(8))) unsigned short ushort8v;
typedef __attribute__((ext_vector_type(4))) float          f32x4v;

__device__ __forceinline__ unsigned short f2bf(float f) {
    unsigned u = __builtin_bit_cast(unsigned, f);
    unsigned r = u + 0x7fffu + ((u >> 16) & 1u);
    return (unsigned short)(r >> 16);
}
__device__ __forceinline__ float bf2f(unsigned short h) {
    return __builtin_bit_cast(float, ((unsigned)h) << 16);
}

// ws layout (floats):
//   ct:      [0, 32768)       fp32 centers transposed ct[d*64+k] (final_dist)
//   ctr:     int @ float 32768 (64 per-cluster arrival counters)
//   c2:      [65536, 65600)
//   cth:     ushort @ float 65600  (64x512 bf16-hi, row-major)
//   ctl:     ushort @ float 81984  (64x512 bf16-lo)
//   rcnt:    int    @ float 98368  (64 clusters x 8 regions)
//   assignv: int    @ float 98880  (32768)
//   part:    float  @ 131648       (64 x 8 x 512 region partial sums)

__global__ void init_centers(const float* __restrict__ x,
                             float* __restrict__ ct,
                             float* __restrict__ c2,
                             unsigned short* __restrict__ cth,
                             unsigned short* __restrict__ ctl,
                             unsigned int* __restrict__ ctr) {
    int k = blockIdx.x;
    int t = threadIdx.x;
    if (t == 0) ctr[k] = 0u;   // reset arrival counters every run (graph replay)
    float ssum = 0.f;
    for (int d = t; d < DIM; d += 256) {
        float v = x[k * DIM + d];
        ct[d * K_CL + k] = v;
        unsigned short h = f2bf(v);
        cth[k * DIM + d] = h;
        ctl[k * DIM + d] = f2bf(v - bf2f(h));
        ssum += v * v;
    }
    #pragma unroll
    for (int off = 32; off; off >>= 1) ssum += __shfl_down(ssum, off);
    __shared__ float red[4];
    if ((t & 63) == 0) red[t >> 6] = ssum;
    __syncthreads();
    if (t == 0) c2[k] = red[0] + red[1] + red[2] + red[3];
}

// ---------------------------------------------------------------------------
// MFMA assignment v2 (unchanged — proven): one wave per 32 points,
// B-operand shared between the two M-tiles. Assignments bitwise identical.
// ---------------------------------------------------------------------------
__device__ __forceinline__ void splitx(const float4 a, const float4 b,
                                       short8v& ah, short8v& al) {
    float fs[8] = {a.x, a.y, a.z, a.w, b.x, b.y, b.z, b.w};
    ushort8v h, l;
    #pragma unroll
    for (int i = 0; i < 8; ++i) {
        unsigned short hh = f2bf(fs[i]);
        h[i] = hh;
        l[i] = f2bf(fs[i] - bf2f(hh));
    }
    ah = __builtin_bit_cast(short8v, h);
    al = __builtin_bit_cast(short8v, l);
}

#define ASTEP(ks_, CUR, NXT)                                                   \
    {                                                                          \
        if ((ks_) < 15) {                                                      \
            _Pragma("unroll")                                                  \
            for (int nt = 0; nt < 4; ++nt) {                                   \
                const size_t off = (size_t)nt * 16 * DIM + ((ks_) + 1) * 32;   \
                bh[NXT][nt] = *(const short8v*)(cbh + off);                    \
                bl[NXT][nt] = *(const short8v*)(cbl + off);                    \
            }                                                                  \
            xr0v[NXT][0] = *(const float4*)(xr0 + ((ks_) + 1) * 32);           \
            xr0v[NXT][1] = *(const float4*)(xr0 + ((ks_) + 1) * 32 + 4);       \
            xr1v[NXT][0] = *(const float4*)(xr1 + ((ks_) + 1) * 32);           \
            xr1v[NXT][1] = *(const float4*)(xr1 + ((ks_) + 1) * 32 + 4);       \
        }                                                                      \
        short8v ah0, al0, ah1, al1;                                            \
        splitx(xr0v[CUR][0], xr0v[CUR][1], ah0, al0);                          \
        splitx(xr1v[CUR][0], xr1v[CUR][1], ah1, al1);                          \
        _Pragma("unroll")                                                      \
        for (int nt = 0; nt < 4; ++nt) {                                       \
            acc0[nt] = __builtin_amdgcn_mfma_f32_16x16x32_bf16(                \
                ah0, bh[CUR][nt], acc0[nt], 0, 0, 0);                          \
            acc0[nt] = __builtin_amdgcn_mfma_f32_16x16x32_bf16(                \
                ah0, bl[CUR][nt], acc0[nt], 0, 0, 0);                          \
            acc0[nt] = __builtin_amdgcn_mfma_f32_16x16x32_bf16(                \
                al0, bh[CUR][nt], acc0[nt], 0, 0, 0);                          \
            acc1[nt] = __builtin_amdgcn_mfma_f32_16x16x32_bf16(                \
                ah1, bh[CUR][nt], acc1[nt], 0, 0, 0);                          \
            acc1[nt] = __builtin_amdgcn_mfma_f32_16x16x32_bf16(                \
                ah1, bl[CUR][nt], acc1[nt], 0, 0, 0);                          \
            acc1[nt] = __builtin_amdgcn_mfma_f32_16x16x32_bf16(                \
                al1, bh[CUR][nt], acc1[nt], 0, 0, 0);                          \
        }                                                                      \
    }

#define ARGMIN_WRITE(ACC, PB)                                                  \
    {                                                                          \
        _Pragma("unroll")                                                      \
        for (int r = 0; r < 4; ++r) {                                          \
            float bv = 1e30f; int bc = 0;                                      \
            _Pragma("unroll")                                                  \
            for (int nt = 0; nt < 4; ++nt) {                                   \
                float v = c2v[nt] - 2.0f * ACC[nt][r];                         \
                if (v < bv) { bv = v; bc = nt * 16 + mrow; }                   \
            }                                                                  \
            _Pragma("unroll")                                                  \
            for (int m = 1; m < 16; m <<= 1) {                                 \
                float ov = __shfl_xor(bv, m);                                  \
                int   oc = __shfl_xor(bc, m);                                  \
                if (ov < bv || (ov == bv && oc < bc)) { bv = ov; bc = oc; }    \
            }                                                                  \
            if (mrow == 0) assignv[(PB) + kgrp * 4 + r] = bc;                  \
        }                                                                      \
    }

__launch_bounds__(64)
__global__ void assign_mfma(const float* __restrict__ x,
                            const unsigned short* __restrict__ cth,
                            const unsigned short* __restrict__ ctl,
                            const float* __restrict__ c2,
                            int* __restrict__ assignv) {
    const int lane  = threadIdx.x;
    const int mbase = blockIdx.x * 32;
    const int mrow  = lane & 15;
    const int kgrp  = lane >> 4;

    const float* xr0 = x + (size_t)(mbase + mrow) * DIM + kgrp * 8;
    const float* xr1 = x + (size_t)(mbase + 16 + mrow) * DIM + kgrp * 8;
    const unsigned short* cbh = cth + (size_t)mrow * DIM + kgrp * 8;
    const unsigned short* cbl = ctl + (size_t)mrow * DIM + kgrp * 8;

    f32x4v acc0[4], acc1[4];
    #pragma unroll
    for (int nt = 0; nt < 4; ++nt) {
        acc0[nt] = (f32x4v){0.f, 0.f, 0.f, 0.f};
        acc1[nt] = (f32x4v){0.f, 0.f, 0.f, 0.f};
    }

    short8v bh[2][4], bl[2][4];
    float4  xr0v[2][2], xr1v[2][2];

    #pragma unroll
    for (int nt = 0; nt < 4; ++nt) {
        const size_t off = (size_t)nt * 16 * DIM;
        bh[0][nt] = *(const short8v*)(cbh + off);
        bl[0][nt] = *(const short8v*)(cbl + off);
    }
    xr0v[0][0] = *(const float4*)(xr0);
    xr0v[0][1] = *(const float4*)(xr0 + 4);
    xr1v[0][0] = *(const float4*)(xr1);
    xr1v[0][1] = *(const float4*)(xr1 + 4);

    for (int kp = 0; kp < 8; ++kp) {
        ASTEP(2 * kp,     0, 1)
        ASTEP(2 * kp + 1, 1, 0)
    }

    float c2v[4];
    #pragma unroll
    for (int nt = 0; nt < 4; ++nt) c2v[nt] = c2[nt * 16 + mrow];

    ARGMIN_WRITE(acc0, mbase)
    ARGMIN_WRITE(acc1, mbase + 16)
}

// ---------------------------------------------------------------------------
// Fused build_lists + gather_part + (last-arrival) update_centers.
// Gather/list phases identical to the proven build_gather. After writing its
// part slice, each (k,pc) block does ONE agent-scope acq_rel atomic on
// ctr[k]; the 8th arrival for cluster k runs the update for that cluster —
// body copied verbatim from update_centers (same thread mapping, same
// pc-ascending sums, same reduction tree) -> ct/cth/ctl/c2 bitwise
// identical. No grid-wide sync (R5 lesson); scope is 8 blocks/cluster and
// the fences overlap other clusters' still-running gathers. Next assign's
// kernel boundary provides grid-wide visibility as before.
// ---------------------------------------------------------------------------
__launch_bounds__(512)
__global__ void build_gather_update(const float* __restrict__ x,
                                    const int* __restrict__ assignv,
                                    int* __restrict__ rcnt,
                                    float* __restrict__ part,
                                    unsigned int* __restrict__ ctr,
                                    float* __restrict__ ct,
                                    float* __restrict__ c2,
                                    unsigned short* __restrict__ cth,
                                    unsigned short* __restrict__ ctl) {
    const int k    = blockIdx.x;
    const int pc   = blockIdx.y;
    const int t    = threadIdx.x;   // 0..511 (dim in gather phase)
    const int lane = t & 63;
    const int w    = t >> 6;        // wave 0..7
    const int p0   = pc * 4096;

    __shared__ int                lst[4096];
    __shared__ unsigned long long msk[64];
    __shared__ int                cnt[64];
    __shared__ int                basel[64];
    __shared__ int                ntot;
    __shared__ int                is_last;
    __shared__ float              red[4];

    #pragma unroll
    for (int j = 0; j < 8; ++j) {
        const int chunk = w * 8 + j;
        const int a = assignv[p0 + chunk * 64 + lane];
        unsigned long long m = __ballot(a == k);
        if (lane == 0) { msk[chunk] = m; cnt[chunk] = __popcll(m); }
    }
    __syncthreads();

    if (w == 0) {
        const int v = cnt[lane];
        int incl = v;
        #pragma unroll
        for (int off = 1; off < 64; off <<= 1) {
            int u = __shfl_up(incl, off);
            if (lane >= off) incl += u;
        }
        basel[lane] = incl - v;
        if (lane == 63) { ntot = incl; rcnt[k * 8 + pc] = incl; }
    }
    __syncthreads();

    #pragma unroll
    for (int j = 0; j < 8; ++j) {
        const int chunk = w * 8 + j;
        const unsigned long long m = msk[chunk];
        if ((m >> lane) & 1ull) {
            const int pos = basel[chunk] +
                __popcll(m & ((1ull << lane) - 1ull));
            lst[pos] = p0 + chunk * 64 + lane;
        }
    }
    __syncthreads();

    const int n = ntot;
    float acc = 0.f;
    int s = 0;
    for (; s + 32 <= n; s += 32) {
        int idx[32];
        #pragma unroll
        for (int q = 0; q < 32; ++q) idx[q] = lst[s + q];
        float v[32];
        #pragma unroll
        for (int q = 0; q < 32; ++q) v[q] = x[(size_t)idx[q] * DIM + t];
        #pragma unroll
        for (int q = 0; q < 32; ++q) acc += v[q];
    }
    for (; s + 8 <= n; s += 8) {
        int idx[8];
        #pragma unroll
        for (int q = 0; q < 8; ++q) idx[q] = lst[s + q];
        #pragma unroll
        for (int q = 0; q < 8; ++q) acc += x[(size_t)idx[q] * DIM + t];
    }
    for (; s < n; ++s) acc += x[(size_t)lst[s] * DIM + t];
    part[((size_t)k * 8 + pc) * DIM + t] = acc;

    // ---- last-arrival update for this cluster ----
    __syncthreads();   // all part writes of this block program-ordered before release
    if (t == 0) {
        unsigned int old = __hip_atomic_fetch_add(&ctr[k], 1u,
                                                  __ATOMIC_ACQ_REL,
                                                  __HIP_MEMORY_SCOPE_AGENT);
        is_last = ((old & 7u) == 7u) ? 1 : 0;
    }
    __syncthreads();
    if (!is_last) return;

    // verbatim update_centers body (threads 0..255 active)
    {
        const bool act = (t < 256);
        float ssum = 0.f;
        if (act) {
            int cntk = 0;
            #pragma unroll
            for (int pq = 0; pq < 8; ++pq) cntk += rcnt[k * 8 + pq];
            float fc = (float)cntk;
            for (int d = t; d < DIM; d += 256) {
                float v = ct[d * K_CL + k];
                if (cntk > 0) {
                    float sm = 0.f;
                    #pragma unroll
                    for (int pq = 0; pq < 8; ++pq)
                        sm += part[((size_t)k * 8 + pq) * DIM + d];
                    v = sm / fc;
                }
                ct[d * K_CL + k] = v;
                unsigned short h = f2bf(v);
                cth[k * DIM + d] = h;
                ctl[k * DIM + d] = f2bf(v - bf2f(h));
                ssum += v * v;
            }
            #pragma unroll
            for (int off = 32; off; off >>= 1) ssum += __shfl_down(ssum, off);
            if ((t & 63) == 0) red[t >> 6] = ssum;
        }
        __syncthreads();
        if (act && t == 0) c2[k] = red[0] + red[1] + red[2] + red[3];
    }
}

// ---------------------------------------------------------------------------
// Final distances via exact fp32 differencing — EXACT R4 configuration
// (best measured: 62.5us, VGPR 92, conflicts 0). P=4 x C=4, 32 pts/block,
// 128 threads, 1024 blocks, LDS 24KB. R3 (P1C4, 32 waves/CU) = 70us and
// R6 (P8C4, 4 waves/CU) = 110us bracket this minimum — do not touch.
// ---------------------------------------------------------------------------
#define DMA_T(tt, bb)                                                          \
    {                                                                          \
        _Pragma("unroll")                                                      \
        for (int q_ = 0; q_ < 4; ++q_) {                                       \
            __builtin_amdgcn_global_load_lds(                                  \
                (const __attribute__((address_space(1))) void*)                \
                    (ct + (tt) * 2048 + q_ * 512 + tid * 4),                   \
                (__attribute__((address_space(3))) void*)                      \
                    (&cs[bb][q_ * 512 + tid * 4]),                             \
                16, 0, 0);                                                     \
        }                                                                      \
        _Pragma("unroll")                                                      \
        for (int q_ = 0; q_ < 2; ++q_) {                                       \
            const int s_   = q_ * 128 + tid;                                   \
            const int row_ = s_ >> 3;                                          \
            const int kq_  = (s_ & 7) ^ (row_ >> 2);                           \
            __builtin_amdgcn_global_load_lds(                                  \
                (const __attribute__((address_space(1))) void*)                \
                    (x + (size_t)(pbase + row_) * DIM +                        \
                     (tt) * 32 + kq_ * 4),                                     \
                (__attribute__((address_space(3))) void*)                      \
                    (&xs[bb][s_ * 4]),                                         \
                16, 0, 0);                                                     \
        }                                                                      \
    }

#define LOADX(sl, kq)                                                          \
    {                                                                          \
        _Pragma("unroll")                                                      \
        for (int i_ = 0; i_ < 4; ++i_)                                         \
            xv[sl][i_] = *(const float4*)(                                     \
                &xs[buf][((rr * 4 + i_) * 8 + ((kq) ^ rr)) * 4]);              \
    }

#define LOADC(sl, kq)                                                          \
    {                                                                          \
        _Pragma("unroll")                                                      \
        for (int j_ = 0; j_ < 4; ++j_)                                         \
            cv[sl][j_] = *(const float4*)(&cs[buf][((kq) * 4 + j_) * 64 +      \
                                                   c * 4]);                    \
    }

#define BODY_DIST(kq)                                                          \
    {                                                                          \
        if ((kq) < 7) { LOADX(((kq) + 1) & 1, (kq) + 1);                       \
                        LOADC(((kq) + 1) & 1, (kq) + 1); }                     \
        const float4 c0 = cv[(kq) & 1][0], c1 = cv[(kq) & 1][1];               \
        const float4 c2v = cv[(kq) & 1][2], c3 = cv[(kq) & 1][3];              \
        _Pragma("unroll")                                                      \
        for (int i = 0; i < 4; ++i) {                                          \
            const float4 xq = xv[(kq) & 1][i];                                 \
            float d0, d1, d2, d3;                                              \
            d0 = xq.x - c0.x;  acc[i][0] += d0 * d0;                           \
            d1 = xq.x - c0.y;  acc[i][1] += d1 * d1;                           \
            d2 = xq.x - c0.z;  acc[i][2] += d2 * d2;                           \
            d3 = xq.x - c0.w;  acc[i][3] += d3 * d3;                           \
            d0 = xq.y - c1.x;  acc[i][0] += d0 * d0;                           \
            d1 = xq.y - c1.y;  acc[i][1] += d1 * d1;                           \
            d2 = xq.y - c1.z;  acc[i][2] += d2 * d2;                           \
            d3 = xq.y - c1.w;  acc[i][3] += d3 * d3;                           \
            d0 = xq.z - c2v.x; acc[i][0] += d0 * d0;                           \
            d1 = xq.z - c2v.y; acc[i][1] += d1 * d1;                           \
            d2 = xq.z - c2v.z; acc[i][2] += d2 * d2;                           \
            d3 = xq.z - c2v.w; acc[i][3] += d3 * d3;                           \
            d0 = xq.w - c3.x;  acc[i][0] += d0 * d0;                           \
            d1 = xq.w - c3.y;  acc[i][1] += d1 * d1;                           \
            d2 = xq.w - c3.z;  acc[i][2] += d2 * d2;                           \
            d3 = xq.w - c3.w;  acc[i][3] += d3 * d3;                           \
        }                                                                      \
    }

__launch_bounds__(128, 2)
__global__ void final_dist(const float* __restrict__ x,
                           const float* __restrict__ ct,
                           float* __restrict__ out) {
    __shared__ float xs[2][1024];   // 32 rows x 8 chunks x 4 floats, swizzled
    __shared__ float cs[2][2048];   // 32 dims x 64 clusters per t-step

    const int tid = threadIdx.x;
    const int pbase = blockIdx.x * 32;
    const int rr = tid >> 4;        // 0..7, four points each
    const int c  = tid & 15;        // 4 clusters each

    float4 xv[2][4];
    float4 cv[2][4];
    float acc[4][4] = {};

    DMA_T(0, 0);
    __syncthreads();

    int buf = 0;
    for (int t = 0; t < 16; ++t) {
        if (t < 15) DMA_T(t + 1, buf ^ 1);
        LOADX(0, 0); LOADC(0, 0);
        BODY_DIST(0); BODY_DIST(1); BODY_DIST(2); BODY_DIST(3);
        BODY_DIST(4); BODY_DIST(5); BODY_DIST(6); BODY_DIST(7);
        __syncthreads();
        buf ^= 1;
    }

    #pragma unroll
    for (int i = 0; i < 4; ++i) {
        int p = pbase + rr * 4 + i;
        float4 o;
        o.x = 1.0f / (sqrtf(acc[i][0]) + EPS_F);
        o.y = 1.0f / (sqrtf(acc[i][1]) + EPS_F);
        o.z = 1.0f / (sqrtf(acc[i][2]) + EPS_F);
        o.w = 1.0f / (sqrtf(acc[i][3]) + EPS_F);
        *(float4*)(out + (size_t)p * K_CL + c * 4) = o;
    }
}

extern "C" void kernel_launch(void* const* d_in, const int* in_sizes, int n_in,
                              void* d_out, int out_size, void* d_ws, size_t ws_size,
                              hipStream_t stream) {
    (void)in_sizes; (void)n_in; (void)out_size; (void)ws_size;
    const float* x = (const float*)d_in[0];
    float* ws      = (float*)d_ws;
    float* ct      = ws;
    unsigned int* ctr = (unsigned int*)(ws + 32768);
    float* c2      = ws + 65536;
    unsigned short* cth = (unsigned short*)(ws + 65600);
    unsigned short* ctl = (unsigned short*)(ws + 81984);
    int*   rcnt    = (int*)(ws + 98368);
    int*   assignv = (int*)(ws + 98880);
    float* part    = ws + 131648;
    float* out     = (float*)d_out;

    init_centers<<<64, 256, 0, stream>>>(x, ct, c2, cth, ctl, ctr);
    for (int it = 0; it < ITERS; ++it) {
        assign_mfma<<<1024, 64, 0, stream>>>(x, cth, ctl, c2, assignv);
        build_gather_update<<<dim3(64, 8), 512, 0, stream>>>(
            x, assignv, rcnt, part, ctr, ct, c2, cth, ctl);
    }
    final_dist<<<1024, 128, 0, stream>>>(x, ct, out);
}

// Round 8
// 631.220 us; speedup vs baseline: 1.2641x; 1.2641x over previous
//
#include <hip/hip_runtime.h>
#include <math.h>

#define N_PTS 32768
#define DIM   512
#define K_CL  64
#define ITERS 10
#define EPS_F 1e-8f

typedef __attribute__((ext_vector_type(8))) short          short8v;
typedef __attribute__((ext_vector_type(8))) unsigned short ushort8v;
typedef __attribute__((ext_vector_type(4))) float          f32x4v;

__device__ __forceinline__ unsigned short f2bf(float f) {
    unsigned u = __builtin_bit_cast(unsigned, f);
    unsigned r = u + 0x7fffu + ((u >> 16) & 1u);
    return (unsigned short)(r >> 16);
}
__device__ __forceinline__ float bf2f(unsigned short h) {
    return __builtin_bit_cast(float, ((unsigned)h) << 16);
}

// ws layout (floats):
//   ct:      [0, 32768)       fp32 centers transposed ct[d*64+k] (final_dist)
//   ctr:     int @ float 32768 (64 per-cluster arrival counters)
//   c2:      [65536, 65600)
//   cth:     ushort @ float 65600  (64x512 bf16-hi, row-major)
//   ctl:     ushort @ float 81984  (64x512 bf16-lo)
//   rcnt:    int    @ float 98368  (64 clusters x 8 regions)
//   assignv: int    @ float 98880  (32768)
//   part:    float  @ 131648       (64 x 8 x 512 region partial sums)

__global__ void init_centers(const float* __restrict__ x,
                             float* __restrict__ ct,
                             float* __restrict__ c2,
                             unsigned short* __restrict__ cth,
                             unsigned short* __restrict__ ctl,
                             unsigned int* __restrict__ ctr) {
    int k = blockIdx.x;
    int t = threadIdx.x;
    if (t == 0) ctr[k] = 0u;   // reset arrival counters every run (graph replay)
    float ssum = 0.f;
    for (int d = t; d < DIM; d += 256) {
        float v = x[k * DIM + d];
        ct[d * K_CL + k] = v;
        unsigned short h = f2bf(v);
        cth[k * DIM + d] = h;
        ctl[k * DIM + d] = f2bf(v - bf2f(h));
        ssum += v * v;
    }
    #pragma unroll
    for (int off = 32; off; off >>= 1) ssum += __shfl_down(ssum, off);
    __shared__ float red[4];
    if ((t & 63) == 0) red[t >> 6] = ssum;
    __syncthreads();
    if (t == 0) c2[k] = red[0] + red[1] + red[2] + red[3];
}

// ---------------------------------------------------------------------------
// MFMA assignment v2 (unchanged — proven): one wave per 32 points,
// B-operand shared between the two M-tiles. Assignments bitwise identical.
// ---------------------------------------------------------------------------
__device__ __forceinline__ void splitx(const float4 a, const float4 b,
                                       short8v& ah, short8v& al) {
    float fs[8] = {a.x, a.y, a.z, a.w, b.x, b.y, b.z, b.w};
    ushort8v h, l;
    #pragma unroll
    for (int i = 0; i < 8; ++i) {
        unsigned short hh = f2bf(fs[i]);
        h[i] = hh;
        l[i] = f2bf(fs[i] - bf2f(hh));
    }
    ah = __builtin_bit_cast(short8v, h);
    al = __builtin_bit_cast(short8v, l);
}

#define ASTEP(ks_, CUR, NXT)                                                   \
    {                                                                          \
        if ((ks_) < 15) {                                                      \
            _Pragma("unroll")                                                  \
            for (int nt = 0; nt < 4; ++nt) {                                   \
                const size_t off = (size_t)nt * 16 * DIM + ((ks_) + 1) * 32;   \
                bh[NXT][nt] = *(const short8v*)(cbh + off);                    \
                bl[NXT][nt] = *(const short8v*)(cbl + off);                    \
            }                                                                  \
            xr0v[NXT][0] = *(const float4*)(xr0 + ((ks_) + 1) * 32);           \
            xr0v[NXT][1] = *(const float4*)(xr0 + ((ks_) + 1) * 32 + 4);       \
            xr1v[NXT][0] = *(const float4*)(xr1 + ((ks_) + 1) * 32);           \
            xr1v[NXT][1] = *(const float4*)(xr1 + ((ks_) + 1) * 32 + 4);       \
        }                                                                      \
        short8v ah0, al0, ah1, al1;                                            \
        splitx(xr0v[CUR][0], xr0v[CUR][1], ah0, al0);                          \
        splitx(xr1v[CUR][0], xr1v[CUR][1], ah1, al1);                          \
        _Pragma("unroll")                                                      \
        for (int nt = 0; nt < 4; ++nt) {                                       \
            acc0[nt] = __builtin_amdgcn_mfma_f32_16x16x32_bf16(                \
                ah0, bh[CUR][nt], acc0[nt], 0, 0, 0);                          \
            acc0[nt] = __builtin_amdgcn_mfma_f32_16x16x32_bf16(                \
                ah0, bl[CUR][nt], acc0[nt], 0, 0, 0);                          \
            acc0[nt] = __builtin_amdgcn_mfma_f32_16x16x32_bf16(                \
                al0, bh[CUR][nt], acc0[nt], 0, 0, 0);                          \
            acc1[nt] = __builtin_amdgcn_mfma_f32_16x16x32_bf16(                \
                ah1, bh[CUR][nt], acc1[nt], 0, 0, 0);                          \
            acc1[nt] = __builtin_amdgcn_mfma_f32_16x16x32_bf16(                \
                ah1, bl[CUR][nt], acc1[nt], 0, 0, 0);                          \
            acc1[nt] = __builtin_amdgcn_mfma_f32_16x16x32_bf16(                \
                al1, bh[CUR][nt], acc1[nt], 0, 0, 0);                          \
        }                                                                      \
    }

#define ARGMIN_WRITE(ACC, PB)                                                  \
    {                                                                          \
        _Pragma("unroll")                                                      \
        for (int r = 0; r < 4; ++r) {                                          \
            float bv = 1e30f; int bc = 0;                                      \
            _Pragma("unroll")                                                  \
            for (int nt = 0; nt < 4; ++nt) {                                   \
                float v = c2v[nt] - 2.0f * ACC[nt][r];                         \
                if (v < bv) { bv = v; bc = nt * 16 + mrow; }                   \
            }                                                                  \
            _Pragma("unroll")                                                  \
            for (int m = 1; m < 16; m <<= 1) {                                 \
                float ov = __shfl_xor(bv, m);                                  \
                int   oc = __shfl_xor(bc, m);                                  \
                if (ov < bv || (ov == bv && oc < bc)) { bv = ov; bc = oc; }    \
            }                                                                  \
            if (mrow == 0) assignv[(PB) + kgrp * 4 + r] = bc;                  \
        }                                                                      \
    }

__launch_bounds__(64)
__global__ void assign_mfma(const float* __restrict__ x,
                            const unsigned short* __restrict__ cth,
                            const unsigned short* __restrict__ ctl,
                            const float* __restrict__ c2,
                            int* __restrict__ assignv) {
    const int lane  = threadIdx.x;
    const int mbase = blockIdx.x * 32;
    const int mrow  = lane & 15;
    const int kgrp  = lane >> 4;

    const float* xr0 = x + (size_t)(mbase + mrow) * DIM + kgrp * 8;
    const float* xr1 = x + (size_t)(mbase + 16 + mrow) * DIM + kgrp * 8;
    const unsigned short* cbh = cth + (size_t)mrow * DIM + kgrp * 8;
    const unsigned short* cbl = ctl + (size_t)mrow * DIM + kgrp * 8;

    f32x4v acc0[4], acc1[4];
    #pragma unroll
    for (int nt = 0; nt < 4; ++nt) {
        acc0[nt] = (f32x4v){0.f, 0.f, 0.f, 0.f};
        acc1[nt] = (f32x4v){0.f, 0.f, 0.f, 0.f};
    }

    short8v bh[2][4], bl[2][4];
    float4  xr0v[2][2], xr1v[2][2];

    #pragma unroll
    for (int nt = 0; nt < 4; ++nt) {
        const size_t off = (size_t)nt * 16 * DIM;
        bh[0][nt] = *(const short8v*)(cbh + off);
        bl[0][nt] = *(const short8v*)(cbl + off);
    }
    xr0v[0][0] = *(const float4*)(xr0);
    xr0v[0][1] = *(const float4*)(xr0 + 4);
    xr1v[0][0] = *(const float4*)(xr1);
    xr1v[0][1] = *(const float4*)(xr1 + 4);

    for (int kp = 0; kp < 8; ++kp) {
        ASTEP(2 * kp,     0, 1)
        ASTEP(2 * kp + 1, 1, 0)
    }

    float c2v[4];
    #pragma unroll
    for (int nt = 0; nt < 4; ++nt) c2v[nt] = c2[nt * 16 + mrow];

    ARGMIN_WRITE(acc0, mbase)
    ARGMIN_WRITE(acc1, mbase + 16)
}

// ---------------------------------------------------------------------------
// Fused build + gather + last-arrival update, v2 fencing.
// R7 lesson: ACQ_REL agent atomics emit buffer_wbl2/buffer_inv per block
// (512 L2 flushes/iter -> +26us/iter, x locality destroyed). v2 uses
// POINT-WISE coherent ops instead — zero cache maintenance instructions:
//   * part/rcnt stores:   __hip_atomic_store(RELAXED, AGENT)  (per-store
//     coherent, bypasses non-coherent L2 path)
//   * ordering:           __syncthreads() (compiler drains vmcnt(0) before
//     s_barrier) THEN relaxed agent fetch_add on ctr[k] — no fence insts
//   * reader (8th block): __hip_atomic_load(RELAXED, AGENT) of part/rcnt
//     (coherence-point reads, immune to stale L2 lines)
// ct reads + all center writes stay plain: those edges cross kernel
// boundaries (launch-time invalidate covers them), never intra-dispatch.
// FP sequences byte-identical to R4 -> ct/cth/ctl/c2 bitwise identical.
// ---------------------------------------------------------------------------
__launch_bounds__(512)
__global__ void build_gather_update(const float* __restrict__ x,
                                    const int* __restrict__ assignv,
                                    int* __restrict__ rcnt,
                                    float* __restrict__ part,
                                    unsigned int* __restrict__ ctr,
                                    float* __restrict__ ct,
                                    float* __restrict__ c2,
                                    unsigned short* __restrict__ cth,
                                    unsigned short* __restrict__ ctl) {
    const int k    = blockIdx.x;
    const int pc   = blockIdx.y;
    const int t    = threadIdx.x;   // 0..511 (dim in gather phase)
    const int lane = t & 63;
    const int w    = t >> 6;        // wave 0..7
    const int p0   = pc * 4096;

    __shared__ int                lst[4096];
    __shared__ unsigned long long msk[64];
    __shared__ int                cnt[64];
    __shared__ int                basel[64];
    __shared__ int                ntot;
    __shared__ int                is_last;
    __shared__ float              red[4];

    #pragma unroll
    for (int j = 0; j < 8; ++j) {
        const int chunk = w * 8 + j;
        const int a = assignv[p0 + chunk * 64 + lane];
        unsigned long long m = __ballot(a == k);
        if (lane == 0) { msk[chunk] = m; cnt[chunk] = __popcll(m); }
    }
    __syncthreads();

    if (w == 0) {
        const int v = cnt[lane];
        int incl = v;
        #pragma unroll
        for (int off = 1; off < 64; off <<= 1) {
            int u = __shfl_up(incl, off);
            if (lane >= off) incl += u;
        }
        basel[lane] = incl - v;
        if (lane == 63) {
            ntot = incl;
            __hip_atomic_store(&rcnt[k * 8 + pc], incl,
                               __ATOMIC_RELAXED, __HIP_MEMORY_SCOPE_AGENT);
        }
    }
    __syncthreads();

    #pragma unroll
    for (int j = 0; j < 8; ++j) {
        const int chunk = w * 8 + j;
        const unsigned long long m = msk[chunk];
        if ((m >> lane) & 1ull) {
            const int pos = basel[chunk] +
                __popcll(m & ((1ull << lane) - 1ull));
            lst[pos] = p0 + chunk * 64 + lane;
        }
    }
    __syncthreads();

    const int n = ntot;
    float acc = 0.f;
    int s = 0;
    for (; s + 32 <= n; s += 32) {
        int idx[32];
        #pragma unroll
        for (int q = 0; q < 32; ++q) idx[q] = lst[s + q];
        float v[32];
        #pragma unroll
        for (int q = 0; q < 32; ++q) v[q] = x[(size_t)idx[q] * DIM + t];
        #pragma unroll
        for (int q = 0; q < 32; ++q) acc += v[q];
    }
    for (; s + 8 <= n; s += 8) {
        int idx[8];
        #pragma unroll
        for (int q = 0; q < 8; ++q) idx[q] = lst[s + q];
        #pragma unroll
        for (int q = 0; q < 8; ++q) acc += x[(size_t)idx[q] * DIM + t];
    }
    for (; s < n; ++s) acc += x[(size_t)lst[s] * DIM + t];
    __hip_atomic_store(&part[((size_t)k * 8 + pc) * DIM + t], acc,
                       __ATOMIC_RELAXED, __HIP_MEMORY_SCOPE_AGENT);

    // ---- last-arrival election (no fences: barrier drains vmcnt first) ----
    __syncthreads();
    if (t == 0) {
        unsigned int old = __hip_atomic_fetch_add(&ctr[k], 1u,
                                                  __ATOMIC_RELAXED,
                                                  __HIP_MEMORY_SCOPE_AGENT);
        is_last = ((old & 7u) == 7u) ? 1 : 0;
    }
    __syncthreads();
    if (!is_last) return;

    // update_centers body; part/rcnt via coherent loads, math identical
    {
        const bool act = (t < 256);
        float ssum = 0.f;
        if (act) {
            int cntk = 0;
            #pragma unroll
            for (int pq = 0; pq < 8; ++pq)
                cntk += __hip_atomic_load(&rcnt[k * 8 + pq],
                                          __ATOMIC_RELAXED,
                                          __HIP_MEMORY_SCOPE_AGENT);
            float fc = (float)cntk;
            for (int d = t; d < DIM; d += 256) {
                float v = ct[d * K_CL + k];
                if (cntk > 0) {
                    float sm = 0.f;
                    #pragma unroll
                    for (int pq = 0; pq < 8; ++pq)
                        sm += __hip_atomic_load(
                            &part[((size_t)k * 8 + pq) * DIM + d],
                            __ATOMIC_RELAXED, __HIP_MEMORY_SCOPE_AGENT);
                    v = sm / fc;
                }
                ct[d * K_CL + k] = v;
                unsigned short h = f2bf(v);
                cth[k * DIM + d] = h;
                ctl[k * DIM + d] = f2bf(v - bf2f(h));
                ssum += v * v;
            }
            #pragma unroll
            for (int off = 32; off; off >>= 1) ssum += __shfl_down(ssum, off);
            if ((t & 63) == 0) red[t >> 6] = ssum;
        }
        __syncthreads();
        if (act && t == 0) c2[k] = red[0] + red[1] + red[2] + red[3];
    }
}

// ---------------------------------------------------------------------------
// Final distances via exact fp32 differencing — EXACT R4 configuration
// (best measured: 62.1us, VGPR 92, conflicts 0). P=4 x C=4, 32 pts/block,
// 128 threads, 1024 blocks, LDS 24KB. R3 (P1C4, 32 waves/CU) = 70us and
// R6 (P8C4, 4 waves/CU) = 110us bracket this minimum — do not touch.
// ---------------------------------------------------------------------------
#define DMA_T(tt, bb)                                                          \
    {                                                                          \
        _Pragma("unroll")                                                      \
        for (int q_ = 0; q_ < 4; ++q_) {                                       \
            __builtin_amdgcn_global_load_lds(                                  \
                (const __attribute__((address_space(1))) void*)                \
                    (ct + (tt) * 2048 + q_ * 512 + tid * 4),                   \
                (__attribute__((address_space(3))) void*)                      \
                    (&cs[bb][q_ * 512 + tid * 4]),                             \
                16, 0, 0);                                                     \
        }                                                                      \
        _Pragma("unroll")                                                      \
        for (int q_ = 0; q_ < 2; ++q_) {                                       \
            const int s_   = q_ * 128 + tid;                                   \
            const int row_ = s_ >> 3;                                          \
            const int kq_  = (s_ & 7) ^ (row_ >> 2);                           \
            __builtin_amdgcn_global_load_lds(                                  \
                (const __attribute__((address_space(1))) void*)                \
                    (x + (size_t)(pbase + row_) * DIM +                        \
                     (tt) * 32 + kq_ * 4),                                     \
                (__attribute__((address_space(3))) void*)                      \
                    (&xs[bb][s_ * 4]),                                         \
                16, 0, 0);                                                     \
        }                                                                      \
    }

#define LOADX(sl, kq)                                                          \
    {                                                                          \
        _Pragma("unroll")                                                      \
        for (int i_ = 0; i_ < 4; ++i_)                                         \
            xv[sl][i_] = *(const float4*)(                                     \
                &xs[buf][((rr * 4 + i_) * 8 + ((kq) ^ rr)) * 4]);              \
    }

#define LOADC(sl, kq)                                                          \
    {                                                                          \
        _Pragma("unroll")                                                      \
        for (int j_ = 0; j_ < 4; ++j_)                                         \
            cv[sl][j_] = *(const float4*)(&cs[buf][((kq) * 4 + j_) * 64 +      \
                                                   c * 4]);                    \
    }

#define BODY_DIST(kq)                                                          \
    {                                                                          \
        if ((kq) < 7) { LOADX(((kq) + 1) & 1, (kq) + 1);                       \
                        LOADC(((kq) + 1) & 1, (kq) + 1); }                     \
        const float4 c0 = cv[(kq) & 1][0], c1 = cv[(kq) & 1][1];               \
        const float4 c2v = cv[(kq) & 1][2], c3 = cv[(kq) & 1][3];              \
        _Pragma("unroll")                                                      \
        for (int i = 0; i < 4; ++i) {                                          \
            const float4 xq = xv[(kq) & 1][i];                                 \
            float d0, d1, d2, d3;                                              \
            d0 = xq.x - c0.x;  acc[i][0] += d0 * d0;                           \
            d1 = xq.x - c0.y;  acc[i][1] += d1 * d1;                           \
            d2 = xq.x - c0.z;  acc[i][2] += d2 * d2;                           \
            d3 = xq.x - c0.w;  acc[i][3] += d3 * d3;                           \
            d0 = xq.y - c1.x;  acc[i][0] += d0 * d0;                           \
            d1 = xq.y - c1.y;  acc[i][1] += d1 * d1;                           \
            d2 = xq.y - c1.z;  acc[i][2] += d2 * d2;                           \
            d3 = xq.y - c1.w;  acc[i][3] += d3 * d3;                           \
            d0 = xq.z - c2v.x; acc[i][0] += d0 * d0;                           \
            d1 = xq.z - c2v.y; acc[i][1] += d1 * d1;                           \
            d2 = xq.z - c2v.z; acc[i][2] += d2 * d2;                           \
            d3 = xq.z - c2v.w; acc[i][3] += d3 * d3;                           \
            d0 = xq.w - c3.x;  acc[i][0] += d0 * d0;                           \
            d1 = xq.w - c3.y;  acc[i][1] += d1 * d1;                           \
            d2 = xq.w - c3.z;  acc[i][2] += d2 * d2;                           \
            d3 = xq.w - c3.w;  acc[i][3] += d3 * d3;                           \
        }                                                                      \
    }

__launch_bounds__(128, 2)
__global__ void final_dist(const float* __restrict__ x,
                           const float* __restrict__ ct,
                           float* __restrict__ out) {
    __shared__ float xs[2][1024];   // 32 rows x 8 chunks x 4 floats, swizzled
    __shared__ float cs[2][2048];   // 32 dims x 64 clusters per t-step

    const int tid = threadIdx.x;
    const int pbase = blockIdx.x * 32;
    const int rr = tid >> 4;        // 0..7, four points each
    const int c  = tid & 15;        // 4 clusters each

    float4 xv[2][4];
    float4 cv[2][4];
    float acc[4][4] = {};

    DMA_T(0, 0);
    __syncthreads();

    int buf = 0;
    for (int t = 0; t < 16; ++t) {
        if (t < 15) DMA_T(t + 1, buf ^ 1);
        LOADX(0, 0); LOADC(0, 0);
        BODY_DIST(0); BODY_DIST(1); BODY_DIST(2); BODY_DIST(3);
        BODY_DIST(4); BODY_DIST(5); BODY_DIST(6); BODY_DIST(7);
        __syncthreads();
        buf ^= 1;
    }

    #pragma unroll
    for (int i = 0; i < 4; ++i) {
        int p = pbase + rr * 4 + i;
        float4 o;
        o.x = 1.0f / (sqrtf(acc[i][0]) + EPS_F);
        o.y = 1.0f / (sqrtf(acc[i][1]) + EPS_F);
        o.z = 1.0f / (sqrtf(acc[i][2]) + EPS_F);
        o.w = 1.0f / (sqrtf(acc[i][3]) + EPS_F);
        *(float4*)(out + (size_t)p * K_CL + c * 4) = o;
    }
}

extern "C" void kernel_launch(void* const* d_in, const int* in_sizes, int n_in,
                              void* d_out, int out_size, void* d_ws, size_t ws_size,
                              hipStream_t stream) {
    (void)in_sizes; (void)n_in; (void)out_size; (void)ws_size;
    const float* x = (const float*)d_in[0];
    float* ws      = (float*)d_ws;
    float* ct      = ws;
    unsigned int* ctr = (unsigned int*)(ws + 32768);
    float* c2      = ws + 65536;
    unsigned short* cth = (unsigned short*)(ws + 65600);
    unsigned short* ctl = (unsigned short*)(ws + 81984);
    int*   rcnt    = (int*)(ws + 98368);
    int*   assignv = (int*)(ws + 98880);
    float* part    = ws + 131648;
    float* out     = (float*)d_out;

    init_centers<<<64, 256, 0, stream>>>(x, ct, c2, cth, ctl, ctr);
    for (int it = 0; it < ITERS; ++it) {
        assign_mfma<<<1024, 64, 0, stream>>>(x, cth, ctl, c2, assignv);
        build_gather_update<<<dim3(64, 8), 512, 0, stream>>>(
            x, assignv, rcnt, part, ctr, ct, c2, cth, ctl);
    }
    final_dist<<<1024, 128, 0, stream>>>(x, ct, out);
}